// Round 5
// baseline (566.594 us; speedup 1.0000x reference)
//
#include <hip/hip_runtime.h>
#include <hip/hip_bf16.h>

#define B_   128
#define S_   128
#define IN_  512
#define H_   256
#define G3_  768   // 3*H
#define C_   256
#define D2H_ 512   // 2*H
#define XPAD 20    // padded b-dim of xp tiles

typedef short bf16x8 __attribute__((ext_vector_type(8)));
typedef float f32x4  __attribute__((ext_vector_type(4)));

static __device__ __forceinline__ short f2bf(float f) {
  unsigned u = __float_as_uint(f);
  return (short)((u + 0x7fffu + ((u >> 16) & 1u)) >> 16);
}
static __device__ __forceinline__ float bf2f(unsigned short v) {
  return __uint_as_float((unsigned)v << 16);
}

// async global->LDS, 16B per lane (LDS dest wave-uniform base, HW adds lane*16)
static __device__ __forceinline__ void async16(const void* g, const void* l) {
  __builtin_amdgcn_global_load_lds(
      (const __attribute__((address_space(1))) void*)g,
      (__attribute__((address_space(3))) void*)l, 16, 0, 0);
}

// ---------------------------------------------------------------------------
// K0: pack n-gate W_hh rows into the MFMA B-fragment stream layout (bf16):
// wnp[((dir*8+wave)*2+tt)*8+kk][lane][j] = whh_n[wave*32+tt*16+(lane&15)]
//                                               [kk*32+(lane>>4)*8+j]
// ---------------------------------------------------------------------------
__global__ __launch_bounds__(1024) void pack_wn(
    const float* __restrict__ whf, const float* __restrict__ whb,
    unsigned short* __restrict__ wnp)
{
  const int o = blockIdx.x * 1024 + threadIdx.x;   // 0..131071
  const int j    = o & 7;
  const int lane = (o >> 3) & 63;
  const int kk   = (o >> 9) & 7;
  const int tt   = (o >> 12) & 1;
  const int wave = (o >> 13) & 7;
  const int dir  = (o >> 16) & 1;
  const float* w = dir ? whb : whf;
  const int row = wave * 32 + tt * 16 + (lane & 15);
  const int k   = kk * 32 + (lane >> 4) * 8 + j;
  wnp[o] = (unsigned short)f2bf(w[(size_t)(2 * H_ + row) * H_ + k]);
}

// ---------------------------------------------------------------------------
// K1: xp = bf16( x @ w_ih^T + b_ih (+ b_hh for r,z) ), both dirs.
// Output layout: xp[t][grp=b/16][g][XPAD]
// ---------------------------------------------------------------------------
__global__ __launch_bounds__(256) void xp_gemm_bf(
    const float* __restrict__ x,
    const float* __restrict__ wf, const float* __restrict__ wb,
    const float* __restrict__ bif, const float* __restrict__ bhf,
    const float* __restrict__ bib, const float* __restrict__ bhb,
    unsigned short* __restrict__ xpf, unsigned short* __restrict__ xpb)
{
  const int sb = blockIdx.x;
  const int bn = blockIdx.y;
  const bool fwd = (bn < 6);
  const float* __restrict__ wsrc = fwd ? wf : wb;
  const float* __restrict__ bi   = fwd ? bif : bib;
  const float* __restrict__ bh   = fwd ? bhf : bhb;
  const int nloc0 = (fwd ? bn : bn - 6) * 128;

  __shared__ __align__(16) unsigned short As[128][56];
  __shared__ __align__(16) unsigned short Bs[128][56];

  const int tid  = threadIdx.x;
  const int wave = tid >> 6, lane = tid & 63;
  const int col  = lane & 15, lg = lane >> 4;
  const int wm   = wave >> 1, wn = wave & 1;
  const int rr   = tid >> 1;
  const int hf   = (tid & 1) * 16;

  const float* ax = x    + ((size_t)(rr * 128 + sb) * IN_ + hf);
  const float* bx = wsrc + ((size_t)(nloc0 + rr) * IN_ + hf);

  f32x4 acc[4][4];
#pragma unroll
  for (int i = 0; i < 4; ++i)
#pragma unroll
    for (int j = 0; j < 4; ++j) acc[i][j] = f32x4{0.f, 0.f, 0.f, 0.f};

  for (int k0 = 0; k0 < IN_; k0 += 32) {
    float4 a0 = *(const float4*)(ax + k0);
    float4 a1 = *(const float4*)(ax + k0 + 4);
    float4 a2 = *(const float4*)(ax + k0 + 8);
    float4 a3 = *(const float4*)(ax + k0 + 12);
    float4 c0 = *(const float4*)(bx + k0);
    float4 c1 = *(const float4*)(bx + k0 + 4);
    float4 c2 = *(const float4*)(bx + k0 + 8);
    float4 c3 = *(const float4*)(bx + k0 + 12);
    __syncthreads();
    {
      bf16x8 p0, p1;
      p0[0]=f2bf(a0.x); p0[1]=f2bf(a0.y); p0[2]=f2bf(a0.z); p0[3]=f2bf(a0.w);
      p0[4]=f2bf(a1.x); p0[5]=f2bf(a1.y); p0[6]=f2bf(a1.z); p0[7]=f2bf(a1.w);
      p1[0]=f2bf(a2.x); p1[1]=f2bf(a2.y); p1[2]=f2bf(a2.z); p1[3]=f2bf(a2.w);
      p1[4]=f2bf(a3.x); p1[5]=f2bf(a3.y); p1[6]=f2bf(a3.z); p1[7]=f2bf(a3.w);
      *(bf16x8*)&As[rr][hf]     = p0;
      *(bf16x8*)&As[rr][hf + 8] = p1;
      p0[0]=f2bf(c0.x); p0[1]=f2bf(c0.y); p0[2]=f2bf(c0.z); p0[3]=f2bf(c0.w);
      p0[4]=f2bf(c1.x); p0[5]=f2bf(c1.y); p0[6]=f2bf(c1.z); p0[7]=f2bf(c1.w);
      p1[0]=f2bf(c2.x); p1[1]=f2bf(c2.y); p1[2]=f2bf(c2.z); p1[3]=f2bf(c2.w);
      p1[4]=f2bf(c3.x); p1[5]=f2bf(c3.y); p1[6]=f2bf(c3.z); p1[7]=f2bf(c3.w);
      *(bf16x8*)&Bs[rr][hf]     = p0;
      *(bf16x8*)&Bs[rr][hf + 8] = p1;
    }
    __syncthreads();
    bf16x8 af[4], bfv[4];
#pragma unroll
    for (int mi = 0; mi < 4; ++mi)
      af[mi] = *(const bf16x8*)&As[wm * 64 + mi * 16 + col][lg * 8];
#pragma unroll
    for (int ni = 0; ni < 4; ++ni)
      bfv[ni] = *(const bf16x8*)&Bs[wn * 64 + ni * 16 + col][lg * 8];
#pragma unroll
    for (int mi = 0; mi < 4; ++mi)
#pragma unroll
      for (int ni = 0; ni < 4; ++ni)
        acc[mi][ni] = __builtin_amdgcn_mfma_f32_16x16x32_bf16(af[mi], bfv[ni], acc[mi][ni], 0, 0, 0);
  }

  const int t = fwd ? sb : (S_ - 1 - sb);
  unsigned short* __restrict__ dstbase = fwd ? xpf : xpb;
#pragma unroll
  for (int ni = 0; ni < 4; ++ni) {
    const int g = nloc0 + wn * 64 + ni * 16 + col;
    const float bias = bi[g] + (g < 2 * H_ ? bh[g] : 0.f);
#pragma unroll
    for (int mi = 0; mi < 4; ++mi) {
      const int grp = wm * 4 + mi;
      ushort4 o;
      o.x = (unsigned short)f2bf(acc[mi][ni][0] + bias);
      o.y = (unsigned short)f2bf(acc[mi][ni][1] + bias);
      o.z = (unsigned short)f2bf(acc[mi][ni][2] + bias);
      o.w = (unsigned short)f2bf(acc[mi][ni][3] + bias);
      *(ushort4*)(dstbase + (((size_t)t * 8 + grp) * G3_ + g) * XPAD + lg * 4) = o;
    }
  }
}

// ---------------------------------------------------------------------------
// K2: GRU recurrence. r,z weights register-resident (128 regs); n weights
// streamed per step from L2 (pre-packed fragments); xp LDS-staged async;
// out-stores deferred one step so they retire under compute.
// ---------------------------------------------------------------------------
__global__ __launch_bounds__(512, 2) void gru_mfma(
    const unsigned short* __restrict__ xpf, const unsigned short* __restrict__ xpb,
    const float* __restrict__ whf, const float* __restrict__ whb,
    const float* __restrict__ bhf, const float* __restrict__ bhb,
    const unsigned short* __restrict__ wnp,
    const int* __restrict__ lens, float* __restrict__ out)
{
  const int dir = blockIdx.x >> 3;
  const int grp = blockIdx.x & 7;
  const int b0  = grp * 16;
  const unsigned short* __restrict__ xp = dir ? xpb : xpf;
  const float* __restrict__ whh = dir ? whb : whf;
  const float* __restrict__ bhh = dir ? bhb : bhf;

  const int tid  = threadIdx.x;
  const int wave = tid >> 6;
  const int lane = tid & 63;
  const int col  = lane & 15;
  const int lg   = lane >> 4;
  const int gb0  = wave * 32 + col;    // tt0 unit; tt1 = +16

  __shared__ __align__(16) unsigned short hlds[2][32][16][8];   // 16KB
  __shared__ __align__(16) unsigned short xlds[2][G3_ * XPAD];  // 60KB

  ((int4*)&hlds[0][0][0][0])[tid] = int4{0, 0, 0, 0};

  // stage t=0
  {
    const unsigned short* base = xp + (size_t)grp * (G3_ * XPAD);
    const char* lb = (const char*)&xlds[0][0];
#pragma unroll
    for (int j = 0; j < 4; ++j) {
      const int c = j * 512 + tid;
      if (c < 1920)
        async16(base + (size_t)c * 8, lb + (size_t)(j * 512 + wave * 64) * 16);
    }
  }

  // r,z weight fragments resident (32 frags = 128 regs)
  bf16x8 wrz[2][2][8];
#pragma unroll
  for (int tt = 0; tt < 2; ++tt) {
    const int gbase = gb0 + tt * 16;
#pragma unroll
    for (int g = 0; g < 2; ++g) {
      const float* wrow = whh + (size_t)(g * H_ + gbase) * H_;
#pragma unroll
      for (int kk = 0; kk < 8; ++kk) {
        const float* pw = wrow + kk * 32 + lg * 8;
        float4 w0 = *(const float4*)pw;
        float4 w1 = *(const float4*)(pw + 4);
        bf16x8 f;
        f[0] = f2bf(w0.x); f[1] = f2bf(w0.y); f[2] = f2bf(w0.z); f[3] = f2bf(w0.w);
        f[4] = f2bf(w1.x); f[5] = f2bf(w1.y); f[6] = f2bf(w1.z); f[7] = f2bf(w1.w);
        wrz[tt][g][kk] = f;
      }
    }
  }

  // n-weight stream base for this wave (chunks of 512 ushorts per (tt,kk))
  const unsigned short* wnb = wnp + ((size_t)(dir * 8 + wave) << 13) + lane * 8;

  float bhn[2];
  bhn[0] = bhh[2 * H_ + gb0];
  bhn[1] = bhh[2 * H_ + gb0 + 16];

  int len_[4];
#pragma unroll
  for (int i = 0; i < 4; ++i) len_[i] = lens[b0 + lg * 4 + i];

  float hreg[2][4] = {};

  // out pointers at s_out(0); advance by +-1 sentence per step
  const int s0 = dir ? (S_ - 1) : 0;
  float* op[4];
#pragma unroll
  for (int i = 0; i < 4; ++i)
    op[i] = out + ((size_t)(b0 + lg * 4 + i) * S_ + s0) * D2H_ + dir * H_ + gb0;
  const ptrdiff_t sdelta = dir ? -(ptrdiff_t)D2H_ : (ptrdiff_t)D2H_;

  int p = 0;
  for (int t = 0; t < S_; ++t) {
    __syncthreads();            // drains vmcnt (staging + prior stores); hlds[p] visible
    const int xb = t & 1;

    // (1) stream this step's n-gate weight fragments (L2-resident, coalesced)
    bf16x8 wn[2][8];
#pragma unroll
    for (int tt = 0; tt < 2; ++tt)
#pragma unroll
      for (int kk = 0; kk < 8; ++kk)
        wn[tt][kk] = *(const bf16x8*)(wnb + ((tt * 8 + kk) << 9));

    // (2) deferred store of h(t-1): retires during this step's compute
    if (t > 0) {
      const int s_prev = dir ? (S_ - t) : (t - 1);
#pragma unroll
      for (int i = 0; i < 4; ++i) {
        const bool m = s_prev < len_[i];
        op[i][0]  = m ? hreg[0][i] : 0.f;
        op[i][16] = m ? hreg[1][i] : 0.f;
        op[i] += sdelta;
      }
    }

    // (3) stage xp(t+1)
    if (t + 1 < S_) {
      const unsigned short* base = xp + ((size_t)(t + 1) * 8 + grp) * (G3_ * XPAD);
      const char* lb = (const char*)&xlds[xb ^ 1][0];
#pragma unroll
      for (int j = 0; j < 4; ++j) {
        const int c = j * 512 + tid;
        if (c < 1920)
          async16(base + (size_t)c * 8, lb + (size_t)(j * 512 + wave * 64) * 16);
      }
    }

    // (4) compute, tt sequential (register pressure)
#pragma unroll
    for (int tt = 0; tt < 2; ++tt) {
      const int u = gb0 + tt * 16;
      ushort4 r4 = *(const ushort4*)&xlds[xb][(size_t)u * XPAD + lg * 4];
      ushort4 z4 = *(const ushort4*)&xlds[xb][(size_t)(H_ + u) * XPAD + lg * 4];
      f32x4 accr, accz, accn;
      accr[0] = bf2f(r4.x); accr[1] = bf2f(r4.y); accr[2] = bf2f(r4.z); accr[3] = bf2f(r4.w);
      accz[0] = bf2f(z4.x); accz[1] = bf2f(z4.y); accz[2] = bf2f(z4.z); accz[3] = bf2f(z4.w);
      accn = f32x4{bhn[tt], bhn[tt], bhn[tt], bhn[tt]};
#pragma unroll
      for (int kk = 0; kk < 8; ++kk) {
        bf16x8 a = *(const bf16x8*)&hlds[p][kk * 4 + lg][col][0];
        accr = __builtin_amdgcn_mfma_f32_16x16x32_bf16(a, wrz[tt][0][kk], accr, 0, 0, 0);
        accz = __builtin_amdgcn_mfma_f32_16x16x32_bf16(a, wrz[tt][1][kk], accz, 0, 0, 0);
        accn = __builtin_amdgcn_mfma_f32_16x16x32_bf16(a, wn[tt][kk], accn, 0, 0, 0);
      }
      ushort4 n4 = *(const ushort4*)&xlds[xb][(size_t)(2 * H_ + u) * XPAD + lg * 4];
      float hnv[4];
#pragma unroll
      for (int i = 0; i < 4; ++i) {
        float r  = 1.f / (1.f + __expf(-accr[i]));
        float z  = 1.f / (1.f + __expf(-accz[i]));
        float nx = bf2f((&n4.x)[i]) + r * accn[i];
        float n  = 1.f - 2.f / (__expf(2.f * nx) + 1.f);
        float hn = n + z * (hreg[tt][i] - n);
        hreg[tt][i] = hn;
        hnv[i] = hn;
      }
      unsigned pk01, pk23;
      asm("v_cvt_pk_bf16_f32 %0, %1, %2" : "=v"(pk01) : "v"(hnv[0]), "v"(hnv[1]));
      asm("v_cvt_pk_bf16_f32 %0, %1, %2" : "=v"(pk23) : "v"(hnv[2]), "v"(hnv[3]));
      const int kb = u >> 3, jj = u & 7;
      hlds[p ^ 1][kb][lg * 4 + 0][jj] = (unsigned short)(pk01 & 0xffffu);
      hlds[p ^ 1][kb][lg * 4 + 1][jj] = (unsigned short)(pk01 >> 16);
      hlds[p ^ 1][kb][lg * 4 + 2][jj] = (unsigned short)(pk23 & 0xffffu);
      hlds[p ^ 1][kb][lg * 4 + 3][jj] = (unsigned short)(pk23 >> 16);
    }
    p ^= 1;
  }

  // epilogue: store h(127)
  {
    const int s_last = dir ? 0 : (S_ - 1);
#pragma unroll
    for (int i = 0; i < 4; ++i) {
      const bool m = s_last < len_[i];
      op[i][0]  = m ? hreg[0][i] : 0.f;
      op[i][16] = m ? hreg[1][i] : 0.f;
    }
  }
}

// ---------------------------------------------------------------------------
// K3: proj[b,s,c] = out[b,s,:] . proj_w[c,:] + proj_b[c]   (fp32)
// ---------------------------------------------------------------------------
__global__ __launch_bounds__(256) void proj_gemm(
    const float* __restrict__ a, const float* __restrict__ w,
    const float* __restrict__ bias, float* __restrict__ proj)
{
  const int bm = blockIdx.x;
  const int n0 = blockIdx.y * 64;

  __shared__ float As[16][68];
  __shared__ float Bs[16][68];

  const int tid = threadIdx.x;
  const int row = tid >> 2;
  const int kq  = (tid & 3) << 2;
  const int tx  = tid & 15, ty = tid >> 4;

  const float* arow = a + (size_t)(bm * 64 + row) * D2H_ + kq;
  const float* brow = w + (size_t)(n0 + row) * D2H_ + kq;

  float acc[4][4] = {};

  for (int k0 = 0; k0 < D2H_; k0 += 16) {
    float4 av = *(const float4*)(arow + k0);
    float4 bv = *(const float4*)(brow + k0);
    As[kq + 0][row] = av.x; As[kq + 1][row] = av.y;
    As[kq + 2][row] = av.z; As[kq + 3][row] = av.w;
    Bs[kq + 0][row] = bv.x; Bs[kq + 1][row] = bv.y;
    Bs[kq + 2][row] = bv.z; Bs[kq + 3][row] = bv.w;
    __syncthreads();
#pragma unroll
    for (int k = 0; k < 16; ++k) {
      float4 av2 = *(const float4*)&As[k][ty * 4];
      float4 bv2 = *(const float4*)&Bs[k][tx * 4];
      acc[0][0] += av2.x * bv2.x; acc[0][1] += av2.x * bv2.y; acc[0][2] += av2.x * bv2.z; acc[0][3] += av2.x * bv2.w;
      acc[1][0] += av2.y * bv2.x; acc[1][1] += av2.y * bv2.y; acc[1][2] += av2.y * bv2.z; acc[1][3] += av2.y * bv2.w;
      acc[2][0] += av2.z * bv2.x; acc[2][1] += av2.z * bv2.y; acc[2][2] += av2.z * bv2.z; acc[2][3] += av2.z * bv2.w;
      acc[3][0] += av2.w * bv2.x; acc[3][1] += av2.w * bv2.y; acc[3][2] += av2.w * bv2.z; acc[3][3] += av2.w * bv2.w;
    }
    __syncthreads();
  }

  float4 bv4 = *(const float4*)(bias + n0 + tx * 4);
#pragma unroll
  for (int i = 0; i < 4; ++i) {
    int m = bm * 64 + ty * 4 + i;
    float4 o;
    o.x = acc[i][0] + bv4.x; o.y = acc[i][1] + bv4.y;
    o.z = acc[i][2] + bv4.z; o.w = acc[i][3] + bv4.w;
    *(float4*)(proj + (size_t)m * C_ + n0 + tx * 4) = o;
  }
}

// ---------------------------------------------------------------------------
__global__ __launch_bounds__(256) void bn_stats(
    const float* __restrict__ proj, float* __restrict__ mu, float* __restrict__ rstd)
{
  const int s = blockIdx.x, tid = threadIdx.x;
  float sum = 0.f, sq = 0.f;
  for (int b = 0; b < B_; ++b) {
    float v = proj[((size_t)b * S_ + s) * C_ + tid];
    sum += v; sq += v * v;
  }
#pragma unroll
  for (int o = 32; o; o >>= 1) { sum += __shfl_down(sum, o); sq += __shfl_down(sq, o); }
  __shared__ float r1[4], r2[4];
  const int lane = tid & 63, wid = tid >> 6;
  if (!lane) { r1[wid] = sum; r2[wid] = sq; }
  __syncthreads();
  if (!tid) {
    float s1 = r1[0] + r1[1] + r1[2] + r1[3];
    float s2 = r2[0] + r2[1] + r2[2] + r2[3];
    float m = s1 / (float)(B_ * C_);
    float var = s2 / (float)(B_ * C_) - m * m;
    mu[s] = m;
    rstd[s] = rsqrtf(var + 1e-5f);
  }
}

__global__ __launch_bounds__(256) void score_k(
    const float* __restrict__ proj, const float* __restrict__ mu,
    const float* __restrict__ rstd, const float* __restrict__ gamma,
    const float* __restrict__ beta, const float* __restrict__ ctx,
    float* __restrict__ scores)
{
  const int wid = threadIdx.x >> 6, lane = threadIdx.x & 63;
  const int m = blockIdx.x * 4 + wid;
  const int s = m & 127;
  float4 v  = *(const float4*)(proj + (size_t)m * C_ + lane * 4);
  float4 cv = *(const float4*)(ctx + lane * 4);
  const float ms = mu[s], rs = rstd[s], g = gamma[s], be = beta[s];
  float acc = fmaxf((v.x - ms) * rs * g + be, 0.f) * cv.x
            + fmaxf((v.y - ms) * rs * g + be, 0.f) * cv.y
            + fmaxf((v.z - ms) * rs * g + be, 0.f) * cv.z
            + fmaxf((v.w - ms) * rs * g + be, 0.f) * cv.w;
#pragma unroll
  for (int o = 32; o; o >>= 1) acc += __shfl_down(acc, o);
  if (!lane) scores[m] = acc;
}

__global__ __launch_bounds__(128) void softmax_k(
    const float* __restrict__ scores, float* __restrict__ attn)
{
  const int b = blockIdx.x, tid = threadIdx.x;
  float v = scores[b * S_ + tid];
  float mx = v;
#pragma unroll
  for (int o = 32; o; o >>= 1) mx = fmaxf(mx, __shfl_down(mx, o));
  __shared__ float t0[2], t1[2];
  const int lane = tid & 63, wid = tid >> 6;
  if (!lane) t0[wid] = mx;
  __syncthreads();
  mx = fmaxf(t0[0], t0[1]);
  float e = __expf(v - mx);
  float ssum = e;
#pragma unroll
  for (int o = 32; o; o >>= 1) ssum += __shfl_down(ssum, o);
  if (!lane) t1[wid] = ssum;
  __syncthreads();
  attn[b * S_ + tid] = e / (t1[0] + t1[1]);
}

__global__ __launch_bounds__(512) void final_k(
    const float* __restrict__ attn, const float* __restrict__ out,
    float* __restrict__ y)
{
  const int b = blockIdx.x, d = threadIdx.x;
  __shared__ float a[S_];
  if (threadIdx.x < S_) a[threadIdx.x] = attn[b * S_ + threadIdx.x];
  __syncthreads();
  float acc = 0.f;
  for (int s = 0; s < S_; ++s)
    acc += a[s] * out[((size_t)b * S_ + s) * D2H_ + d];
  y[(size_t)b * D2H_ + d] = acc;
}

// ---------------------------------------------------------------------------
extern "C" void kernel_launch(void* const* d_in, const int* in_sizes, int n_in,
                              void* d_out, int out_size, void* d_ws, size_t ws_size,
                              hipStream_t stream)
{
  const float* x      = (const float*)d_in[0];
  const int*   lens   = (const int*)d_in[2];
  const float* w_ih_f = (const float*)d_in[3];
  const float* w_hh_f = (const float*)d_in[4];
  const float* b_ih_f = (const float*)d_in[5];
  const float* b_hh_f = (const float*)d_in[6];
  const float* w_ih_b = (const float*)d_in[7];
  const float* w_hh_b = (const float*)d_in[8];
  const float* b_ih_b = (const float*)d_in[9];
  const float* b_hh_b = (const float*)d_in[10];
  const float* proj_w = (const float*)d_in[11];
  const float* proj_b = (const float*)d_in[12];
  const float* gamma  = (const float*)d_in[13];
  const float* beta   = (const float*)d_in[14];
  const float* ctx    = (const float*)d_in[15];

  float* ws = (float*)d_ws;
  // outm 32MB | xpf 30MB | xpb 30MB | wnp 256KB   (< 128 MiB)
  float* outm = ws;                                        //  8,388,608 f
  unsigned short* xpf = (unsigned short*)(ws + 8388608);   // 15,728,640 us
  unsigned short* xpb = xpf + 15728640;                    // 15,728,640 us
  unsigned short* wnp = xpb + 15728640;                    //    131,072 us
  // epilogue aliases (xp dead after gru):
  float* proj   = ws + 8388608;                            //  4,194,304 f
  float* mu     = ws + 12582912;
  float* rstd   = ws + 12583040;
  float* scores = ws + 12583168;
  float* attn   = ws + 12599552;

  pack_wn<<<128, 1024, 0, stream>>>(w_hh_f, w_hh_b, wnp);
  xp_gemm_bf<<<dim3(128, 12), 256, 0, stream>>>(
      x, w_ih_f, w_ih_b, b_ih_f, b_hh_f, b_ih_b, b_hh_b, xpf, xpb);
  gru_mfma<<<16, 512, 0, stream>>>(xpf, xpb, w_hh_f, w_hh_b, b_hh_f, b_hh_b,
                                   wnp, lens, outm);
  proj_gemm<<<dim3(256, 4), 256, 0, stream>>>(outm, proj_w, proj_b, proj);
  bn_stats<<<128, 256, 0, stream>>>(proj, mu, rstd);
  score_k<<<4096, 256, 0, stream>>>(proj, mu, rstd, gamma, beta, ctx, scores);
  softmax_k<<<128, 128, 0, stream>>>(scores, attn);
  final_k<<<128, 512, 0, stream>>>(attn, outm, (float*)d_out);
}

// Round 6
// 460.779 us; speedup vs baseline: 1.2296x; 1.2296x over previous
//
#include <hip/hip_runtime.h>
#include <hip/hip_bf16.h>

#define B_   128
#define S_   128
#define IN_  512
#define H_   256
#define G3_  768   // 3*H
#define C_   256
#define D2H_ 512   // 2*H

typedef short bf16x8 __attribute__((ext_vector_type(8)));
typedef float f32x4  __attribute__((ext_vector_type(4)));

static __device__ __forceinline__ short f2bf(float f) {
  unsigned u = __float_as_uint(f);
  return (short)((u + 0x7fffu + ((u >> 16) & 1u)) >> 16);
}
static __device__ __forceinline__ float bf2f(unsigned short v) {
  return __uint_as_float((unsigned)v << 16);
}

// async global->LDS, 16B per lane (LDS dest wave-uniform base, HW adds lane*16)
static __device__ __forceinline__ void async16(const void* g, const void* l) {
  __builtin_amdgcn_global_load_lds(
      (const __attribute__((address_space(1))) void*)g,
      (__attribute__((address_space(3))) void*)l, 16, 0, 0);
}

// ---------------------------------------------------------------------------
// K0: pack ALL W_hh gate rows into MFMA B-fragment stream layout (bf16):
// wp[(((((dir*8+wave)*3+g)*2+tt)*8+kk)*64+lane)*8+j]
//   = whh[dir][g*H + wave*32+tt*16+(lane&15)][kk*32+(lane>>4)*8+j]
// ---------------------------------------------------------------------------
__global__ __launch_bounds__(1024) void pack_wh(
    const float* __restrict__ whf, const float* __restrict__ whb,
    unsigned short* __restrict__ wp)
{
  const int o = blockIdx.x * 1024 + threadIdx.x;   // 0..393215
  const int j    = o & 7;
  const int lane = (o >> 3) & 63;
  const int kk   = (o >> 9) & 7;
  const int tt   = (o >> 12) & 1;
  const int rest = o >> 13;
  const int g    = rest % 3;
  const int wv   = (rest / 3) & 7;
  const int dir  = rest / 24;
  const float* w = dir ? whb : whf;
  const int row = wv * 32 + tt * 16 + (lane & 15);
  const int k   = kk * 32 + (lane >> 4) * 8 + j;
  wp[o] = (unsigned short)f2bf(w[(size_t)(g * H_ + row) * H_ + k]);
}

// ---------------------------------------------------------------------------
// K1: xp = bf16( x @ w_ih^T + b_ih (+ b_hh for r,z) ), both dirs.
// Output layout: xp[t][grp=b/4][g][4]  (bf16; per-(t,grp) slice 6144B contig)
// ---------------------------------------------------------------------------
__global__ __launch_bounds__(256) void xp_gemm_bf(
    const float* __restrict__ x,
    const float* __restrict__ wf, const float* __restrict__ wb,
    const float* __restrict__ bif, const float* __restrict__ bhf,
    const float* __restrict__ bib, const float* __restrict__ bhb,
    unsigned short* __restrict__ xpf, unsigned short* __restrict__ xpb)
{
  const int sb = blockIdx.x;
  const int bn = blockIdx.y;
  const bool fwd = (bn < 6);
  const float* __restrict__ wsrc = fwd ? wf : wb;
  const float* __restrict__ bi   = fwd ? bif : bib;
  const float* __restrict__ bh   = fwd ? bhf : bhb;
  const int nloc0 = (fwd ? bn : bn - 6) * 128;

  __shared__ __align__(16) unsigned short As[128][56];
  __shared__ __align__(16) unsigned short Bs[128][56];

  const int tid  = threadIdx.x;
  const int wave = tid >> 6, lane = tid & 63;
  const int col  = lane & 15, lg = lane >> 4;
  const int wm   = wave >> 1, wn = wave & 1;
  const int rr   = tid >> 1;
  const int hf   = (tid & 1) * 16;

  const float* ax = x    + ((size_t)(rr * 128 + sb) * IN_ + hf);
  const float* bx = wsrc + ((size_t)(nloc0 + rr) * IN_ + hf);

  f32x4 acc[4][4];
#pragma unroll
  for (int i = 0; i < 4; ++i)
#pragma unroll
    for (int j = 0; j < 4; ++j) acc[i][j] = f32x4{0.f, 0.f, 0.f, 0.f};

  for (int k0 = 0; k0 < IN_; k0 += 32) {
    float4 a0 = *(const float4*)(ax + k0);
    float4 a1 = *(const float4*)(ax + k0 + 4);
    float4 a2 = *(const float4*)(ax + k0 + 8);
    float4 a3 = *(const float4*)(ax + k0 + 12);
    float4 c0 = *(const float4*)(bx + k0);
    float4 c1 = *(const float4*)(bx + k0 + 4);
    float4 c2 = *(const float4*)(bx + k0 + 8);
    float4 c3 = *(const float4*)(bx + k0 + 12);
    __syncthreads();
    {
      bf16x8 p0, p1;
      p0[0]=f2bf(a0.x); p0[1]=f2bf(a0.y); p0[2]=f2bf(a0.z); p0[3]=f2bf(a0.w);
      p0[4]=f2bf(a1.x); p0[5]=f2bf(a1.y); p0[6]=f2bf(a1.z); p0[7]=f2bf(a1.w);
      p1[0]=f2bf(a2.x); p1[1]=f2bf(a2.y); p1[2]=f2bf(a2.z); p1[3]=f2bf(a2.w);
      p1[4]=f2bf(a3.x); p1[5]=f2bf(a3.y); p1[6]=f2bf(a3.z); p1[7]=f2bf(a3.w);
      *(bf16x8*)&As[rr][hf]     = p0;
      *(bf16x8*)&As[rr][hf + 8] = p1;
      p0[0]=f2bf(c0.x); p0[1]=f2bf(c0.y); p0[2]=f2bf(c0.z); p0[3]=f2bf(c0.w);
      p0[4]=f2bf(c1.x); p0[5]=f2bf(c1.y); p0[6]=f2bf(c1.z); p0[7]=f2bf(c1.w);
      p1[0]=f2bf(c2.x); p1[1]=f2bf(c2.y); p1[2]=f2bf(c2.z); p1[3]=f2bf(c2.w);
      p1[4]=f2bf(c3.x); p1[5]=f2bf(c3.y); p1[6]=f2bf(c3.z); p1[7]=f2bf(c3.w);
      *(bf16x8*)&Bs[rr][hf]     = p0;
      *(bf16x8*)&Bs[rr][hf + 8] = p1;
    }
    __syncthreads();
    bf16x8 af[4], bfv[4];
#pragma unroll
    for (int mi = 0; mi < 4; ++mi)
      af[mi] = *(const bf16x8*)&As[wm * 64 + mi * 16 + col][lg * 8];
#pragma unroll
    for (int ni = 0; ni < 4; ++ni)
      bfv[ni] = *(const bf16x8*)&Bs[wn * 64 + ni * 16 + col][lg * 8];
#pragma unroll
    for (int mi = 0; mi < 4; ++mi)
#pragma unroll
      for (int ni = 0; ni < 4; ++ni)
        acc[mi][ni] = __builtin_amdgcn_mfma_f32_16x16x32_bf16(af[mi], bfv[ni], acc[mi][ni], 0, 0, 0);
  }

  const int t = fwd ? sb : (S_ - 1 - sb);
  unsigned short* __restrict__ dstbase = fwd ? xpf : xpb;
#pragma unroll
  for (int ni = 0; ni < 4; ++ni) {
    const int g = nloc0 + wn * 64 + ni * 16 + col;
    const float bias = bi[g] + (g < 2 * H_ ? bh[g] : 0.f);
#pragma unroll
    for (int mi = 0; mi < 4; ++mi) {
      const int grp = wm * 16 + mi * 4 + lg;             // b/4
      ushort4 o;
      o.x = (unsigned short)f2bf(acc[mi][ni][0] + bias);
      o.y = (unsigned short)f2bf(acc[mi][ni][1] + bias);
      o.z = (unsigned short)f2bf(acc[mi][ni][2] + bias);
      o.w = (unsigned short)f2bf(acc[mi][ni][3] + bias);
      *(ushort4*)(dstbase + (((size_t)t * 32 + grp) * G3_ + g) * 4) = o;
    }
  }
}

// ---------------------------------------------------------------------------
// K2: GRU recurrence. 64 blocks = 2 dirs x 32 groups of 4 batches (64 CUs).
// r,z weights register-resident (pre-packed bf16 frags); n streamed from L2;
// xp staged 6KB/step via global_load_lds (dbuf); out-stores deferred a step.
// Valid batches live in A rows 0-3 / C rows 0-3 (lg==0 lanes); rows 4-15 zero.
// ---------------------------------------------------------------------------
__global__ __launch_bounds__(512, 2) void gru_mfma(
    const unsigned short* __restrict__ xpf, const unsigned short* __restrict__ xpb,
    const unsigned short* __restrict__ wp,
    const float* __restrict__ bhf, const float* __restrict__ bhb,
    const int* __restrict__ lens, float* __restrict__ out)
{
  const int dir  = blockIdx.x >> 5;
  const int grpb = blockIdx.x & 31;
  const int b0   = grpb * 4;
  const unsigned short* __restrict__ xp = dir ? xpb : xpf;
  const float* __restrict__ bhh = dir ? bhb : bhf;

  const int tid  = threadIdx.x;
  const int wave = tid >> 6;
  const int lane = tid & 63;
  const int col  = lane & 15;
  const int lg   = lane >> 4;
  const int gb0  = wave * 32 + col;    // tt0 unit; tt1 = +16

  __shared__ __align__(16) unsigned short hlds[2][32][16][8];   // 16KB
  __shared__ __align__(16) unsigned short xlds[2][G3_ * 4];     // 12KB

  // zero BOTH h buffers (rows 4-15 must stay zero forever)
  ((int4*)hlds)[tid]       = int4{0, 0, 0, 0};
  ((int4*)hlds)[512 + tid] = int4{0, 0, 0, 0};

  // stage t=0 (384 granules of 16B; waves 6,7 idle)
  {
    const unsigned short* base = xp + (size_t)grpb * (G3_ * 4);
    if (tid < 384)
      async16(base + (size_t)tid * 8, (const char*)&xlds[0][0] + wave * 1024);
  }

  // packed fragment base for this (dir, wave)
  const unsigned short* wpb = wp + (size_t)(dir * 8 + wave) * 24576 + lane * 8;

  // r,z weight fragments resident (32 frags = 128 regs)
  bf16x8 wrz[2][2][8];
#pragma unroll
  for (int tt = 0; tt < 2; ++tt)
#pragma unroll
    for (int g = 0; g < 2; ++g)
#pragma unroll
      for (int kk = 0; kk < 8; ++kk)
        wrz[tt][g][kk] = *(const bf16x8*)(wpb + (((g * 2 + tt) * 8 + kk) << 9));

  float bhn[2];
  bhn[0] = bhh[2 * H_ + gb0];
  bhn[1] = bhh[2 * H_ + gb0 + 16];

  int len_[4];
#pragma unroll
  for (int i = 0; i < 4; ++i) len_[i] = lens[b0 + i];

  float hreg[2][4] = {};

  // out pointers at s_out(0); advance +-1 sentence per step (lg==0 lanes use)
  const int s0 = dir ? (S_ - 1) : 0;
  float* op[4];
#pragma unroll
  for (int i = 0; i < 4; ++i)
    op[i] = out + ((size_t)(b0 + i) * S_ + s0) * D2H_ + dir * H_ + gb0;
  const ptrdiff_t sdelta = dir ? -(ptrdiff_t)D2H_ : (ptrdiff_t)D2H_;

  int p = 0;
  for (int t = 0; t < S_; ++t) {
    __syncthreads();            // drains vmcnt: xlds[t&1] staged; hlds[p] visible
    const int xb = t & 1;

    // (1) stream this step's n-gate fragments (L2-resident, shared by 32 blocks)
    bf16x8 wn[2][8];
#pragma unroll
    for (int tt = 0; tt < 2; ++tt)
#pragma unroll
      for (int kk = 0; kk < 8; ++kk)
        wn[tt][kk] = *(const bf16x8*)(wpb + (((4 + tt) * 8 + kk) << 9));

    // (2) deferred store of h(t-1)
    if (t > 0 && lg == 0) {
      const int s_prev = dir ? (S_ - t) : (t - 1);
#pragma unroll
      for (int i = 0; i < 4; ++i) {
        const bool m = s_prev < len_[i];
        op[i][0]  = m ? hreg[0][i] : 0.f;
        op[i][16] = m ? hreg[1][i] : 0.f;
        op[i] += sdelta;
      }
    }

    // (3) stage xp(t+1)
    if (t + 1 < S_) {
      const unsigned short* base = xp + ((size_t)(t + 1) * 32 + grpb) * (G3_ * 4);
      if (tid < 384)
        async16(base + (size_t)tid * 8, (const char*)&xlds[xb ^ 1][0] + wave * 1024);
    }

    // (4) compute
#pragma unroll
    for (int tt = 0; tt < 2; ++tt) {
      const int u = gb0 + tt * 16;
      ushort4 r4 = *(const ushort4*)&xlds[xb][u * 4];
      ushort4 z4 = *(const ushort4*)&xlds[xb][(H_ + u) * 4];
      f32x4 accr, accz, accn;
      accr[0] = bf2f(r4.x); accr[1] = bf2f(r4.y); accr[2] = bf2f(r4.z); accr[3] = bf2f(r4.w);
      accz[0] = bf2f(z4.x); accz[1] = bf2f(z4.y); accz[2] = bf2f(z4.z); accz[3] = bf2f(z4.w);
      accn = f32x4{bhn[tt], bhn[tt], bhn[tt], bhn[tt]};
#pragma unroll
      for (int kk = 0; kk < 8; ++kk) {
        bf16x8 a = *(const bf16x8*)&hlds[p][kk * 4 + lg][col][0];
        accr = __builtin_amdgcn_mfma_f32_16x16x32_bf16(a, wrz[tt][0][kk], accr, 0, 0, 0);
        accz = __builtin_amdgcn_mfma_f32_16x16x32_bf16(a, wrz[tt][1][kk], accz, 0, 0, 0);
        accn = __builtin_amdgcn_mfma_f32_16x16x32_bf16(a, wn[tt][kk], accn, 0, 0, 0);
      }
      ushort4 n4 = *(const ushort4*)&xlds[xb][(2 * H_ + u) * 4];
      float hnv[4];
#pragma unroll
      for (int i = 0; i < 4; ++i) {
        float r  = 1.f / (1.f + __expf(-accr[i]));
        float z  = 1.f / (1.f + __expf(-accz[i]));
        float nx = bf2f((&n4.x)[i]) + r * accn[i];
        float n  = 1.f - 2.f / (__expf(2.f * nx) + 1.f);
        float hn = n + z * (hreg[tt][i] - n);
        hreg[tt][i] = hn;
        hnv[i] = hn;
      }
      if (lg == 0) {
        unsigned pk01, pk23;
        asm("v_cvt_pk_bf16_f32 %0, %1, %2" : "=v"(pk01) : "v"(hnv[0]), "v"(hnv[1]));
        asm("v_cvt_pk_bf16_f32 %0, %1, %2" : "=v"(pk23) : "v"(hnv[2]), "v"(hnv[3]));
        const int kb = u >> 3, jj = u & 7;
        hlds[p ^ 1][kb][0][jj] = (unsigned short)(pk01 & 0xffffu);
        hlds[p ^ 1][kb][1][jj] = (unsigned short)(pk01 >> 16);
        hlds[p ^ 1][kb][2][jj] = (unsigned short)(pk23 & 0xffffu);
        hlds[p ^ 1][kb][3][jj] = (unsigned short)(pk23 >> 16);
      }
    }
    p ^= 1;
  }

  // epilogue: store h(127)
  if (lg == 0) {
    const int s_last = dir ? 0 : (S_ - 1);
#pragma unroll
    for (int i = 0; i < 4; ++i) {
      const bool m = s_last < len_[i];
      op[i][0]  = m ? hreg[0][i] : 0.f;
      op[i][16] = m ? hreg[1][i] : 0.f;
    }
  }
}

// ---------------------------------------------------------------------------
// K3: proj[b,s,c] = out[b,s,:] . proj_w[c,:] + proj_b[c]   (fp32)
// ---------------------------------------------------------------------------
__global__ __launch_bounds__(256) void proj_gemm(
    const float* __restrict__ a, const float* __restrict__ w,
    const float* __restrict__ bias, float* __restrict__ proj)
{
  const int bm = blockIdx.x;
  const int n0 = blockIdx.y * 64;

  __shared__ float As[16][68];
  __shared__ float Bs[16][68];

  const int tid = threadIdx.x;
  const int row = tid >> 2;
  const int kq  = (tid & 3) << 2;
  const int tx  = tid & 15, ty = tid >> 4;

  const float* arow = a + (size_t)(bm * 64 + row) * D2H_ + kq;
  const float* brow = w + (size_t)(n0 + row) * D2H_ + kq;

  float acc[4][4] = {};

  for (int k0 = 0; k0 < D2H_; k0 += 16) {
    float4 av = *(const float4*)(arow + k0);
    float4 bv = *(const float4*)(brow + k0);
    As[kq + 0][row] = av.x; As[kq + 1][row] = av.y;
    As[kq + 2][row] = av.z; As[kq + 3][row] = av.w;
    Bs[kq + 0][row] = bv.x; Bs[kq + 1][row] = bv.y;
    Bs[kq + 2][row] = bv.z; Bs[kq + 3][row] = bv.w;
    __syncthreads();
#pragma unroll
    for (int k = 0; k < 16; ++k) {
      float4 av2 = *(const float4*)&As[k][ty * 4];
      float4 bv2 = *(const float4*)&Bs[k][tx * 4];
      acc[0][0] += av2.x * bv2.x; acc[0][1] += av2.x * bv2.y; acc[0][2] += av2.x * bv2.z; acc[0][3] += av2.x * bv2.w;
      acc[1][0] += av2.y * bv2.x; acc[1][1] += av2.y * bv2.y; acc[1][2] += av2.y * bv2.z; acc[1][3] += av2.y * bv2.w;
      acc[2][0] += av2.z * bv2.x; acc[2][1] += av2.z * bv2.y; acc[2][2] += av2.z * bv2.z; acc[2][3] += av2.z * bv2.w;
      acc[3][0] += av2.w * bv2.x; acc[3][1] += av2.w * bv2.y; acc[3][2] += av2.w * bv2.z; acc[3][3] += av2.w * bv2.w;
    }
    __syncthreads();
  }

  float4 bv4 = *(const float4*)(bias + n0 + tx * 4);
#pragma unroll
  for (int i = 0; i < 4; ++i) {
    int m = bm * 64 + ty * 4 + i;
    float4 o;
    o.x = acc[i][0] + bv4.x; o.y = acc[i][1] + bv4.y;
    o.z = acc[i][2] + bv4.z; o.w = acc[i][3] + bv4.w;
    *(float4*)(proj + (size_t)m * C_ + n0 + tx * 4) = o;
  }
}

// ---------------------------------------------------------------------------
__global__ __launch_bounds__(256) void bn_stats(
    const float* __restrict__ proj, float* __restrict__ mu, float* __restrict__ rstd)
{
  const int s = blockIdx.x, tid = threadIdx.x;
  float sum = 0.f, sq = 0.f;
  for (int b = 0; b < B_; ++b) {
    float v = proj[((size_t)b * S_ + s) * C_ + tid];
    sum += v; sq += v * v;
  }
#pragma unroll
  for (int o = 32; o; o >>= 1) { sum += __shfl_down(sum, o); sq += __shfl_down(sq, o); }
  __shared__ float r1[4], r2[4];
  const int lane = tid & 63, wid = tid >> 6;
  if (!lane) { r1[wid] = sum; r2[wid] = sq; }
  __syncthreads();
  if (!tid) {
    float s1 = r1[0] + r1[1] + r1[2] + r1[3];
    float s2 = r2[0] + r2[1] + r2[2] + r2[3];
    float m = s1 / (float)(B_ * C_);
    float var = s2 / (float)(B_ * C_) - m * m;
    mu[s] = m;
    rstd[s] = rsqrtf(var + 1e-5f);
  }
}

__global__ __launch_bounds__(256) void score_k(
    const float* __restrict__ proj, const float* __restrict__ mu,
    const float* __restrict__ rstd, const float* __restrict__ gamma,
    const float* __restrict__ beta, const float* __restrict__ ctx,
    float* __restrict__ scores)
{
  const int wid = threadIdx.x >> 6, lane = threadIdx.x & 63;
  const int m = blockIdx.x * 4 + wid;
  const int s = m & 127;
  float4 v  = *(const float4*)(proj + (size_t)m * C_ + lane * 4);
  float4 cv = *(const float4*)(ctx + lane * 4);
  const float ms = mu[s], rs = rstd[s], g = gamma[s], be = beta[s];
  float acc = fmaxf((v.x - ms) * rs * g + be, 0.f) * cv.x
            + fmaxf((v.y - ms) * rs * g + be, 0.f) * cv.y
            + fmaxf((v.z - ms) * rs * g + be, 0.f) * cv.z
            + fmaxf((v.w - ms) * rs * g + be, 0.f) * cv.w;
#pragma unroll
  for (int o = 32; o; o >>= 1) acc += __shfl_down(acc, o);
  if (!lane) scores[m] = acc;
}

__global__ __launch_bounds__(128) void softmax_k(
    const float* __restrict__ scores, float* __restrict__ attn)
{
  const int b = blockIdx.x, tid = threadIdx.x;
  float v = scores[b * S_ + tid];
  float mx = v;
#pragma unroll
  for (int o = 32; o; o >>= 1) mx = fmaxf(mx, __shfl_down(mx, o));
  __shared__ float t0[2], t1[2];
  const int lane = tid & 63, wid = tid >> 6;
  if (!lane) t0[wid] = mx;
  __syncthreads();
  mx = fmaxf(t0[0], t0[1]);
  float e = __expf(v - mx);
  float ssum = e;
#pragma unroll
  for (int o = 32; o; o >>= 1) ssum += __shfl_down(ssum, o);
  if (!lane) t1[wid] = ssum;
  __syncthreads();
  attn[b * S_ + tid] = e / (t1[0] + t1[1]);
}

__global__ __launch_bounds__(512) void final_k(
    const float* __restrict__ attn, const float* __restrict__ out,
    float* __restrict__ y)
{
  const int b = blockIdx.x, d = threadIdx.x;
  __shared__ float a[S_];
  if (threadIdx.x < S_) a[threadIdx.x] = attn[b * S_ + threadIdx.x];
  __syncthreads();
  float acc = 0.f;
  for (int s = 0; s < S_; ++s)
    acc += a[s] * out[((size_t)b * S_ + s) * D2H_ + d];
  y[(size_t)b * D2H_ + d] = acc;
}

// ---------------------------------------------------------------------------
extern "C" void kernel_launch(void* const* d_in, const int* in_sizes, int n_in,
                              void* d_out, int out_size, void* d_ws, size_t ws_size,
                              hipStream_t stream)
{
  const float* x      = (const float*)d_in[0];
  const int*   lens   = (const int*)d_in[2];
  const float* w_ih_f = (const float*)d_in[3];
  const float* w_hh_f = (const float*)d_in[4];
  const float* b_ih_f = (const float*)d_in[5];
  const float* b_hh_f = (const float*)d_in[6];
  const float* w_ih_b = (const float*)d_in[7];
  const float* w_hh_b = (const float*)d_in[8];
  const float* b_ih_b = (const float*)d_in[9];
  const float* b_hh_b = (const float*)d_in[10];
  const float* proj_w = (const float*)d_in[11];
  const float* proj_b = (const float*)d_in[12];
  const float* gamma  = (const float*)d_in[13];
  const float* beta   = (const float*)d_in[14];
  const float* ctx    = (const float*)d_in[15];

  float* ws = (float*)d_ws;
  // outm 32MB | xpf 24MB | xpb 24MB | wp 768KB  (~81 MB)
  float* outm = ws;                                        //  8,388,608 f
  unsigned short* xpf = (unsigned short*)(ws + 8388608);   // 12,582,912 us
  unsigned short* xpb = xpf + 12582912;                    // 12,582,912 us
  unsigned short* wp  = xpb + 12582912;                    //    393,216 us
  // epilogue aliases (xp dead after gru):
  float* proj   = ws + 8388608;                            //  4,194,304 f
  float* mu     = ws + 12582912;
  float* rstd   = ws + 12583040;
  float* scores = ws + 12583168;
  float* attn   = ws + 12599552;

  pack_wh<<<384, 1024, 0, stream>>>(w_hh_f, w_hh_b, wp);
  xp_gemm_bf<<<dim3(128, 12), 256, 0, stream>>>(
      x, w_ih_f, w_ih_b, b_ih_f, b_hh_f, b_ih_b, b_hh_b, xpf, xpb);
  gru_mfma<<<64, 512, 0, stream>>>(xpf, xpb, wp, b_hh_f, b_hh_b, lens, outm);
  proj_gemm<<<dim3(256, 4), 256, 0, stream>>>(outm, proj_w, proj_b, proj);
  bn_stats<<<128, 256, 0, stream>>>(proj, mu, rstd);
  score_k<<<4096, 256, 0, stream>>>(proj, mu, rstd, gamma, beta, ctx, scores);
  softmax_k<<<128, 128, 0, stream>>>(scores, attn);
  final_k<<<128, 512, 0, stream>>>(attn, outm, (float*)d_out);
}